// Round 3
// baseline (3114.644 us; speedup 1.0000x reference)
//
#include <hip/hip_runtime.h>
#include <cfloat>

// Problem dims (fixed by reference): z_e [8,2048,768] f32, embedding [8192,768] f32.
#define NROWS 16384
#define DIM   768
#define KC    8192

// Pass-1 tiling
#define TM 32            // rows per block
#define TN 256           // codes per compute sub-tile
#define DT 16            // D-chunk staged in LDS
#define KT_PER_BLK 4     // sub-tiles per block -> 1024 codes/block
#define TKBLK (TN * KT_PER_BLK)   // 1024
#define KBLKS (KC / TKBLK)        // 8 code-blocks per row
#define NBLKS (NROWS / TM)        // 512 row-blocks

// ---------------------------------------------------------------------------
// K1: x2[n] = np.sum(z*z, axis=1) in f32, replicating numpy pairwise order
// bitwise: 768 -> 384+384 -> 192+192 -> 96(base). base96: 8 accumulators,
// 11 sequential adds each, tree ((r0+r1)+(r2+r3))+((r4+r5)+(r6+r7)).
// Chunk combine = same xor-tree shape. f32 add is commutative, so shfl_xor
// pairing reproduces the exact tree. FMA contraction must stay OFF here.
// ---------------------------------------------------------------------------
__global__ __launch_bounds__(256)
void x2_kernel(const float* __restrict__ z, float* __restrict__ x2,
               double* __restrict__ loss_acc) {
#pragma clang fp contract(off)
  if (blockIdx.x == 0 && threadIdx.x == 0) loss_acc[0] = 0.0;
  const int n     = blockIdx.x * 4 + (threadIdx.x >> 6);  // one wave per row
  const int lane  = threadIdx.x & 63;
  const int chunk = lane >> 3;   // 0..7 : numpy 96-element base block
  const int j     = lane & 7;    // 0..7 : accumulator index in base block
  const float* p  = z + (size_t)n * DIM + chunk * 96 + j;
  float v0 = p[0];
  float r  = v0 * v0;
  #pragma unroll
  for (int k = 1; k < 12; ++k) {
    const float v  = p[8 * k];
    const float sq = v * v;     // elementwise square rounded first (no fma)
    r = r + sq;
  }
  r = r + __shfl_xor(r, 1);     // (r0+r1) level
  r = r + __shfl_xor(r, 2);     // ((r0+r1)+(r2+r3))
  r = r + __shfl_xor(r, 4);     // base-96 result
  r = r + __shfl_xor(r, 8);     // 192 = 96+96
  r = r + __shfl_xor(r, 16);    // 384 = 192+192
  r = r + __shfl_xor(r, 32);    // 768 = 384+384
  if (lane == 0) x2[n] = r;
}

// ---------------------------------------------------------------------------
// K2: fused f32 GEMM + per-(row, code-block) argmin of d = x2[n] - 2*dot,
//     exactly the reference f32 score (||e||^2 provably absorbed: < ulp/2).
//     dot = single sequential-k fmaf chain (matches BLAS k-order accumulate).
//     Ties (common: scores sit on the 2^-14 grid) -> lowest index.
// ---------------------------------------------------------------------------
__global__ __launch_bounds__(256)
void pass1(const float* __restrict__ z, const float* __restrict__ emb,
           const float* __restrict__ x2, float* __restrict__ mval,
           int* __restrict__ midx) {
  __shared__ float As[DT][TM];      // A transposed: [d][row]
  __shared__ float Bs[DT][TN];      // B transposed: [d][code]
  __shared__ float x2s[TM];
  __shared__ float redv[TM][33];    // final per-row merge (+1 pad)
  __shared__ int   redi[TM][33];

  const int t    = threadIdx.x;
  const int row0 = blockIdx.x * TM;
  const int kblk = blockIdx.y;
  const int rg   = t >> 5;          // 0..7  : 4-row group
  const int cg   = t & 31;          // 0..31 : 8-col group

  if (t < TM) x2s[t] = x2[row0 + t];

  // per-thread running best over this block's 1024 codes (ascending c order)
  float bv[4]; int bi[4];
  #pragma unroll
  for (int i = 0; i < 4; ++i) { bv[i] = FLT_MAX; bi[i] = 0; }

  for (int kt = 0; kt < KT_PER_BLK; ++kt) {
    const int cbase = kblk * TKBLK + kt * TN;
    float acc[4][8];
    #pragma unroll
    for (int i = 0; i < 4; ++i)
      #pragma unroll
      for (int j = 0; j < 8; ++j) acc[i][j] = 0.f;

    for (int dc = 0; dc < DIM; dc += DT) {
      // stage A: 32 rows x 16 d (512 floats, threads 0..127)
      if (t < 128) {
        const int r = t >> 2, dq = (t & 3) << 2;
        const float4 a = *(const float4*)(z + (size_t)(row0 + r) * DIM + dc + dq);
        As[dq + 0][r] = a.x; As[dq + 1][r] = a.y;
        As[dq + 2][r] = a.z; As[dq + 3][r] = a.w;
      }
      // stage B: 256 codes x 16 d, one code per thread (64B contiguous/lane)
      {
        const float* src = emb + (size_t)(cbase + t) * DIM + dc;
        const float4 b0 = *(const float4*)(src);
        const float4 b1 = *(const float4*)(src + 4);
        const float4 b2 = *(const float4*)(src + 8);
        const float4 b3 = *(const float4*)(src + 12);
        Bs[0][t]  = b0.x; Bs[1][t]  = b0.y; Bs[2][t]  = b0.z; Bs[3][t]  = b0.w;
        Bs[4][t]  = b1.x; Bs[5][t]  = b1.y; Bs[6][t]  = b1.z; Bs[7][t]  = b1.w;
        Bs[8][t]  = b2.x; Bs[9][t]  = b2.y; Bs[10][t] = b2.z; Bs[11][t] = b2.w;
        Bs[12][t] = b3.x; Bs[13][t] = b3.y; Bs[14][t] = b3.z; Bs[15][t] = b3.w;
      }
      __syncthreads();
      #pragma unroll
      for (int d = 0; d < DT; ++d) {
        const float4 av  = *(const float4*)&As[d][rg << 2];
        const float4 bv0 = *(const float4*)&Bs[d][cg << 3];
        const float4 bv1 = *(const float4*)&Bs[d][(cg << 3) + 4];
        const float a4[4] = {av.x, av.y, av.z, av.w};
        const float b8[8] = {bv0.x, bv0.y, bv0.z, bv0.w,
                             bv1.x, bv1.y, bv1.z, bv1.w};
        #pragma unroll
        for (int i = 0; i < 4; ++i)
          #pragma unroll
          for (int j = 0; j < 8; ++j)
            acc[i][j] = fmaf(a4[i], b8[j], acc[i][j]);   // k-sequential chain
      }
      __syncthreads();
    }

    // reference f32 score; per-thread min, ascending c + strict < = lowest idx
    #pragma unroll
    for (int j = 0; j < 8; ++j) {
      const int c = cbase + (cg << 3) + j;
      #pragma unroll
      for (int i = 0; i < 4; ++i) {
        const float m = 2.0f * acc[i][j];        // exact (power of two)
        const float d = x2s[(rg << 2) + i] - m;  // single f32 rounding
        if (d < bv[i]) { bv[i] = d; bi[i] = c; }
      }
    }
  }

  // cross-thread merge: (value, index) lexicographic — ties are REAL here
  #pragma unroll
  for (int i = 0; i < 4; ++i) {
    redv[(rg << 2) + i][cg] = bv[i];
    redi[(rg << 2) + i][cg] = bi[i];
  }
  __syncthreads();
  if (t < TM) {
    float rv = FLT_MAX; int ri = 0x7fffffff;
    for (int g = 0; g < 32; ++g) {
      const float v = redv[t][g]; const int ai = redi[t][g];
      if (v < rv || (v == rv && ai < ri)) { rv = v; ri = ai; }
    }
    const size_t base = (size_t)(row0 + t) * KBLKS + kblk;
    mval[base] = rv;
    midx[base] = ri;
  }
}

// ---------------------------------------------------------------------------
// K3: per row (one wave): merge 8 block winners (ascending kblk, strict < +
//     index tie-break), gather + straight-through output + loss partial
// ---------------------------------------------------------------------------
__global__ __launch_bounds__(256)
void pass2(const float* __restrict__ z, const float* __restrict__ emb,
           const float* __restrict__ mval, const int* __restrict__ midx,
           float* __restrict__ out, double* __restrict__ loss_acc) {
  const int lane = threadIdx.x & 63;
  const int n    = blockIdx.x * 4 + (threadIdx.x >> 6);

  float bv = FLT_MAX; int bi = 0x7fffffff;
  for (int k = 0; k < KBLKS; ++k) {      // ascending kblk = ascending c-range
    const float v = mval[(size_t)n * KBLKS + k];
    const int   c = midx[(size_t)n * KBLKS + k];
    if (v < bv || (v == bv && c < bi)) { bv = v; bi = c; }
  }

  const float* zr = z + (size_t)n * DIM;
  const float* er = emb + (size_t)bi * DIM;
  double lsum = 0.0;
  #pragma unroll
  for (int i = 0; i < 12; ++i) {
    const float zz = zr[lane + 64 * i];
    const float q  = er[lane + 64 * i];
    out[(size_t)n * DIM + lane + 64 * i] = zz + (q - zz);  // ST, ref f32 ops
    const float d1 = q - zz;
    lsum = fma((double)d1, (double)d1, lsum);
  }
  #pragma unroll
  for (int off = 32; off; off >>= 1) lsum += __shfl_xor(lsum, off);
  if (lane == 0) {
    out[(size_t)NROWS * DIM + n] = (float)bi;   // indices as f32 values
    atomicAdd(loss_acc, lsum);
  }
}

// ---------------------------------------------------------------------------
// K4: loss = 0.25 * mean
// ---------------------------------------------------------------------------
__global__ void fin_kernel(const double* __restrict__ loss_acc,
                           float* __restrict__ out) {
  out[(size_t)NROWS * DIM + NROWS] =
      (float)(0.25 * loss_acc[0] / (double)((size_t)NROWS * DIM));
}

extern "C" void kernel_launch(void* const* d_in, const int* in_sizes, int n_in,
                              void* d_out, int out_size, void* d_ws, size_t ws_size,
                              hipStream_t stream) {
  const float* z   = (const float*)d_in[0];
  const float* emb = (const float*)d_in[1];
  float* out = (float*)d_out;
  char*  ws  = (char*)d_ws;

  // ws: [0] double loss_acc | [256] f32 x2[NROWS] | f32 mval[NROWS*KBLKS]
  //     | int midx[NROWS*KBLKS]
  double* loss_acc = (double*)ws;
  float*  x2       = (float*)(ws + 256);
  float*  mval     = (float*)(ws + 256 + sizeof(float) * NROWS);
  int*    midx     = (int*)(ws + 256 + sizeof(float) * NROWS
                                     + sizeof(float) * NROWS * KBLKS);

  x2_kernel<<<NROWS / 4, 256, 0, stream>>>(z, x2, loss_acc);
  pass1<<<dim3(NBLKS, KBLKS), 256, 0, stream>>>(z, emb, x2, mval, midx);
  pass2<<<NROWS / 4, 256, 0, stream>>>(z, emb, mval, midx, out, loss_acc);
  fin_kernel<<<1, 1, 0, stream>>>(loss_acc, out);
}

// Round 4
// 743.152 us; speedup vs baseline: 4.1911x; 4.1911x over previous
//
#include <hip/hip_runtime.h>
#include <cfloat>

// Problem dims (fixed): z_e [8,2048,768] f32, embedding [8192,768] f32.
#define NROWS 16384
#define DIM   768
#define KC    8192
#define MARGIN 4e-4f

typedef unsigned short ushort_t;
typedef __attribute__((ext_vector_type(8))) short short8v;  // 8 bf16 (4 VGPR)
typedef __attribute__((ext_vector_type(4))) float f32x4;

// RN-even f32->bf16 (finite inputs only)
__device__ __forceinline__ ushort_t f2bf(float f) {
  unsigned u = __float_as_uint(f);
  return (ushort_t)((u + 0x7FFFu + ((u >> 16) & 1u)) >> 16);
}

// async global->LDS, 16B per lane. LDS dest = wave-uniform base + lane*16.
__device__ __forceinline__ void gload_lds16(const void* g, void* l) {
  using GP = const __attribute__((address_space(1))) void*;
  using LP = __attribute__((address_space(3))) void*;
  GP gp = (GP)(unsigned long long)(uintptr_t)g;
  LP lp = (LP)(unsigned)(uintptr_t)l;     // low 32b of flat LDS addr = LDS offset
  __builtin_amdgcn_global_load_lds(gp, lp, 16, 0, 0);
}

// ---------------------------------------------------------------------------
// K0: f32 -> bf16 convert (8 elems/thread, fully coalesced)
// ---------------------------------------------------------------------------
__global__ __launch_bounds__(256)
void cvt_kernel(const float* __restrict__ src, ushort_t* __restrict__ dst, int n8) {
  const int i = blockIdx.x * 256 + threadIdx.x;
  if (i >= n8) return;
  const float4* s4 = (const float4*)src;
  const float4 f0 = s4[2 * i], f1 = s4[2 * i + 1];
  uint4 o;
  o.x = (unsigned)f2bf(f0.x) | ((unsigned)f2bf(f0.y) << 16);
  o.y = (unsigned)f2bf(f0.z) | ((unsigned)f2bf(f0.w) << 16);
  o.z = (unsigned)f2bf(f1.x) | ((unsigned)f2bf(f1.y) << 16);
  o.w = (unsigned)f2bf(f1.z) | ((unsigned)f2bf(f1.w) << 16);
  ((uint4*)dst)[i] = o;
}

// ---------------------------------------------------------------------------
// K1: x2[n] = np.sum(z*z, axis=1) bitwise (pairwise order) — proven in r3.
// ---------------------------------------------------------------------------
__global__ __launch_bounds__(256)
void x2_kernel(const float* __restrict__ z, float* __restrict__ x2,
               double* __restrict__ loss_acc) {
#pragma clang fp contract(off)
  if (blockIdx.x == 0 && threadIdx.x == 0) loss_acc[0] = 0.0;
  const int n     = blockIdx.x * 4 + (threadIdx.x >> 6);
  const int lane  = threadIdx.x & 63;
  const int chunk = lane >> 3;
  const int j     = lane & 7;
  const float* p  = z + (size_t)n * DIM + chunk * 96 + j;
  float v0 = p[0];
  float r  = v0 * v0;
  #pragma unroll
  for (int k = 1; k < 12; ++k) {
    const float v  = p[8 * k];
    const float sq = v * v;
    r = r + sq;
  }
  r = r + __shfl_xor(r, 1);
  r = r + __shfl_xor(r, 2);
  r = r + __shfl_xor(r, 4);
  r = r + __shfl_xor(r, 8);
  r = r + __shfl_xor(r, 16);
  r = r + __shfl_xor(r, 32);
  if (lane == 0) x2[n] = r;
}

// ---------------------------------------------------------------------------
// K2: bf16 MFMA GEMM (128x128 tile, BK=32) + per-(row, 128-code block) top-2
//     of approx v = -2*dot_bf16. XOR-swizzled LDS (slot' = slot ^ ((r>>1)&3))
//     with pre-swizzled global source (both-sides rule).
// ---------------------------------------------------------------------------
__global__ __launch_bounds__(256)
void gemm1(const ushort_t* __restrict__ zh, const ushort_t* __restrict__ eh,
           float4* __restrict__ subtop) {
  __shared__ __align__(16) ushort_t Ash[128 * 32];
  __shared__ __align__(16) ushort_t Bsh[128 * 32];
  __shared__ float4 ltop[128][2];

  const int t    = threadIdx.x;
  const int w    = t >> 6, lane = t & 63;
  const int wr   = w >> 1, wc = w & 1;
  const int row0 = blockIdx.y * 128;
  const int col0 = blockIdx.x * 128;

  f32x4 acc[4][4];
  #pragma unroll
  for (int m = 0; m < 4; ++m)
    #pragma unroll
    for (int n = 0; n < 4; ++n) acc[m][n] = (f32x4){0.f, 0.f, 0.f, 0.f};

  const int rbase = w * 32 + (lane >> 2);   // staged row (q=0), +16 for q=1
  const int jslot = lane & 3;               // dest 16B slot within 64B row

  for (int kk = 0; kk < DIM; kk += 32) {
    // ---- stage A,B: per wave 2 issues each, 16 rows x 32k per issue ----
    #pragma unroll
    for (int q = 0; q < 2; ++q) {
      const int r = rbase + q * 16;
      const int j = jslot ^ ((r >> 1) & 3);           // pre-swizzled source
      gload_lds16(zh + (size_t)(row0 + r) * DIM + kk + j * 8,
                  &Ash[w * 1024 + q * 512]);
      gload_lds16(eh + (size_t)(col0 + r) * DIM + kk + j * 8,
                  &Bsh[w * 1024 + q * 512]);
    }
    __syncthreads();
    // ---- frags + MFMA ----
    short8v a[4], b[4];
    #pragma unroll
    for (int m = 0; m < 4; ++m) {
      const int r  = wr * 64 + m * 16 + (lane & 15);
      const int ja = (lane >> 4) ^ ((r >> 1) & 3);
      a[m] = *(const short8v*)&Ash[r * 32 + ja * 8];
      const int c  = wc * 64 + m * 16 + (lane & 15);
      const int jb = (lane >> 4) ^ ((c >> 1) & 3);
      b[m] = *(const short8v*)&Bsh[c * 32 + jb * 8];
    }
    #pragma unroll
    for (int m = 0; m < 4; ++m)
      #pragma unroll
      for (int n = 0; n < 4; ++n)
        acc[m][n] = __builtin_amdgcn_mfma_f32_16x16x32_bf16(a[m], b[n], acc[m][n], 0, 0, 0);
    __syncthreads();
  }

  // ---- epilogue: per-row top-2 over this block's 128 codes ----
  #pragma unroll
  for (int m = 0; m < 4; ++m) {
    #pragma unroll
    for (int reg = 0; reg < 4; ++reg) {
      float v1 = FLT_MAX, v2 = FLT_MAX; int i1 = 0, i2 = 0;
      #pragma unroll
      for (int n = 0; n < 4; ++n) {
        const float v = -2.0f * acc[m][n][reg];
        const int   c = col0 + wc * 64 + n * 16 + (lane & 15);
        if (v < v1)      { v2 = v1; i2 = i1; v1 = v; i1 = c; }
        else if (v < v2) { v2 = v; i2 = c; }
      }
      #pragma unroll
      for (int off = 1; off < 16; off <<= 1) {
        const float ov1 = __shfl_xor(v1, off); const int oi1 = __shfl_xor(i1, off);
        const float ov2 = __shfl_xor(v2, off); const int oi2 = __shfl_xor(i2, off);
        if (ov1 < v1) {
          const float nv2 = (v1 < ov2) ? v1 : ov2;
          const int   ni2 = (v1 < ov2) ? i1 : oi2;
          v1 = ov1; i1 = oi1; v2 = nv2; i2 = ni2;
        } else if (ov1 < v2) { v2 = ov1; i2 = oi1; }
      }
      const int rloc = wr * 64 + m * 16 + (lane >> 4) * 4 + reg;
      if ((lane & 15) == 0)
        ltop[rloc][wc] = make_float4(v1, __int_as_float(i1), v2, __int_as_float(i2));
    }
  }
  __syncthreads();
  if (t < 128) {
    const float4 P = ltop[t][0], Q = ltop[t][1];
    float v1, v2; int i1, i2;
    if (P.x <= Q.x) {
      v1 = P.x; i1 = __float_as_int(P.y);
      v2 = (P.z < Q.x) ? P.z : Q.x;
      i2 = (P.z < Q.x) ? __float_as_int(P.w) : __float_as_int(Q.y);
    } else {
      v1 = Q.x; i1 = __float_as_int(Q.y);
      v2 = (Q.z < P.x) ? Q.z : P.x;
      i2 = (Q.z < P.x) ? __float_as_int(Q.w) : __float_as_int(P.y);
    }
    subtop[(size_t)(row0 + t) * 64 + blockIdx.x] =
        make_float4(v1, __int_as_float(i1), v2, __int_as_float(i2));
  }
}

// ---------------------------------------------------------------------------
// K3: per row (1 wave): margin shortlist -> exact f32-chain rescore ->
//     winner -> gather + straight-through + loss (proven r3 semantics).
// ---------------------------------------------------------------------------
__global__ __launch_bounds__(256)
void finalize(const float* __restrict__ z, const float* __restrict__ emb,
              const float* __restrict__ x2, const float4* __restrict__ subtop,
              float* __restrict__ out, double* __restrict__ loss_acc) {
  const int lane = threadIdx.x & 63;
  const int n    = blockIdx.x * 4 + (threadIdx.x >> 6);

  const float4 e = subtop[(size_t)n * 64 + lane];
  const float v1 = e.x; const int i1 = __float_as_int(e.y);
  const float v2 = e.z;

  float rowmin = v1;
  #pragma unroll
  for (int off = 32; off; off >>= 1) rowmin = fminf(rowmin, __shfl_xor(rowmin, off));
  const float thr = rowmin + MARGIN;

  const unsigned long long mA = __ballot(v1 <= thr);
  const unsigned long long mB = __ballot(v2 <= thr);

  const float* zr  = z + (size_t)n * DIM;
  const float  x2n = x2[n];
  float bd = FLT_MAX; int bc = 0x7fffffff;

  // full-block rescore (rare): 128 codes, 2 per lane
  unsigned long long m = mB;
  while (m) {
    const int s = __builtin_ctzll(m); m &= m - 1;
    const int c0 = s * 128 + lane;
    const float* e0p = emb + (size_t)c0 * DIM;
    const float* e1p = e0p + (size_t)64 * DIM;
    float d0 = 0.f, d1 = 0.f;
    #pragma unroll 4
    for (int k = 0; k < DIM; ++k) {
      const float zk = zr[k];
      d0 = fmaf(zk, e0p[k], d0);
      d1 = fmaf(zk, e1p[k], d1);
    }
    const float s0 = x2n - 2.0f * d0;
    const float s1 = x2n - 2.0f * d1;
    if (s0 < bd || (s0 == bd && c0 < bc)) { bd = s0; bc = c0; }
    const int c1 = c0 + 64;
    if (s1 < bd || (s1 == bd && c1 < bc)) { bd = s1; bc = c1; }
  }
  // singles: exact chain, all lanes redundant
  m = mA & ~mB;
  while (m) {
    const int s = __builtin_ctzll(m); m &= m - 1;
    const int c = __shfl(i1, s);
    const float* ep = emb + (size_t)c * DIM;
    float d = 0.f;
    #pragma unroll 8
    for (int k = 0; k < DIM; ++k) d = fmaf(zr[k], ep[k], d);
    const float sv = x2n - 2.0f * d;
    if (sv < bd || (sv == bd && c < bc)) { bd = sv; bc = c; }
  }
  // wave lexicographic (value, index) min
  #pragma unroll
  for (int off = 32; off; off >>= 1) {
    const float ov = __shfl_xor(bd, off);
    const int   oc = __shfl_xor(bc, off);
    if (ov < bd || (ov == bd && oc < bc)) { bd = ov; bc = oc; }
  }

  // output: straight-through + indices + loss partial
  const float* er = emb + (size_t)bc * DIM;
  double lsum = 0.0;
  #pragma unroll
  for (int i = 0; i < 12; ++i) {
    const int   idx = lane + 64 * i;
    const float zz  = zr[idx];
    const float q   = er[idx];
    out[(size_t)n * DIM + idx] = zz + (q - zz);
    const float d1 = q - zz;
    lsum = fma((double)d1, (double)d1, lsum);
  }
  #pragma unroll
  for (int off = 32; off; off >>= 1) lsum += __shfl_xor(lsum, off);
  if (lane == 0) {
    out[(size_t)NROWS * DIM + n] = (float)bc;
    atomicAdd(loss_acc, lsum);
  }
}

// ---------------------------------------------------------------------------
// K4: loss = 0.25 * mean
// ---------------------------------------------------------------------------
__global__ void fin_kernel(const double* __restrict__ loss_acc,
                           float* __restrict__ out) {
  out[(size_t)NROWS * DIM + NROWS] =
      (float)(0.25 * loss_acc[0] / (double)((size_t)NROWS * DIM));
}

extern "C" void kernel_launch(void* const* d_in, const int* in_sizes, int n_in,
                              void* d_out, int out_size, void* d_ws, size_t ws_size,
                              hipStream_t stream) {
  const float* z   = (const float*)d_in[0];
  const float* emb = (const float*)d_in[1];
  float* out = (float*)d_out;
  char*  ws  = (char*)d_ws;

  // ws: loss(256B) | x2 64KB | zh 24MB | eh 12MB | subtop 16MB  (~54.6MB)
  double*   loss_acc = (double*)ws;
  float*    x2       = (float*)(ws + 256);
  ushort_t* zh       = (ushort_t*)(ws + 65792);
  ushort_t* eh       = (ushort_t*)(ws + 25231616);
  float4*   subtop   = (float4*)(ws + 37814528);

  cvt_kernel<<<(NROWS * DIM / 8 + 255) / 256, 256, 0, stream>>>(z, zh, NROWS * DIM / 8);
  cvt_kernel<<<(KC * DIM / 8 + 255) / 256, 256, 0, stream>>>(emb, eh, KC * DIM / 8);
  x2_kernel<<<NROWS / 4, 256, 0, stream>>>(z, x2, loss_acc);
  gemm1<<<dim3(KC / 128, NROWS / 128), 256, 0, stream>>>(zh, eh, subtop);
  finalize<<<NROWS / 4, 256, 0, stream>>>(z, emb, x2, subtop, out, loss_acc);
  fin_kernel<<<1, 1, 0, stream>>>(loss_acc, out);
}

// Round 5
// 497.369 us; speedup vs baseline: 6.2622x; 1.4942x over previous
//
#include <hip/hip_runtime.h>
#include <cfloat>

// Problem dims (fixed): z_e [8,2048,768] f32, embedding [8192,768] f32.
#define NROWS 16384
#define DIM   768
#define KC    8192
#define MARGIN 4e-4f
#define NBLK_EMIT (NROWS / 4)   // 4096 blocks, 4 rows each

typedef unsigned short ushort_t;
typedef __attribute__((ext_vector_type(8))) short short8v;  // 8 bf16 (4 VGPR)
typedef __attribute__((ext_vector_type(4))) float f32x4;

// RN-even f32->bf16 (finite inputs only)
__device__ __forceinline__ ushort_t f2bf(float f) {
  unsigned u = __float_as_uint(f);
  return (ushort_t)((u + 0x7FFFu + ((u >> 16) & 1u)) >> 16);
}

// async global->LDS, 16B per lane. LDS dest = wave-uniform base + lane*16.
__device__ __forceinline__ void gload_lds16(const void* g, void* l) {
  using GP = const __attribute__((address_space(1))) void*;
  using LP = __attribute__((address_space(3))) void*;
  GP gp = (GP)(unsigned long long)(uintptr_t)g;
  LP lp = (LP)(unsigned)(uintptr_t)l;
  __builtin_amdgcn_global_load_lds(gp, lp, 16, 0, 0);
}

// ---------------------------------------------------------------------------
// K0: f32 -> bf16 convert (8 elems/thread, fully coalesced)
// ---------------------------------------------------------------------------
__global__ __launch_bounds__(256)
void cvt_kernel(const float* __restrict__ src, ushort_t* __restrict__ dst, int n8) {
  const int i = blockIdx.x * 256 + threadIdx.x;
  if (i >= n8) return;
  const float4* s4 = (const float4*)src;
  const float4 f0 = s4[2 * i], f1 = s4[2 * i + 1];
  uint4 o;
  o.x = (unsigned)f2bf(f0.x) | ((unsigned)f2bf(f0.y) << 16);
  o.y = (unsigned)f2bf(f0.z) | ((unsigned)f2bf(f0.w) << 16);
  o.z = (unsigned)f2bf(f1.x) | ((unsigned)f2bf(f1.y) << 16);
  o.w = (unsigned)f2bf(f1.z) | ((unsigned)f2bf(f1.w) << 16);
  ((uint4*)dst)[i] = o;
}

// ---------------------------------------------------------------------------
// K1: x2[n] = np.sum(z*z, axis=1) bitwise (pairwise order) — proven in r3.
// ---------------------------------------------------------------------------
__global__ __launch_bounds__(256)
void x2_kernel(const float* __restrict__ z, float* __restrict__ x2) {
#pragma clang fp contract(off)
  const int n     = blockIdx.x * 4 + (threadIdx.x >> 6);
  const int lane  = threadIdx.x & 63;
  const int chunk = lane >> 3;
  const int j     = lane & 7;
  const float* p  = z + (size_t)n * DIM + chunk * 96 + j;
  float v0 = p[0];
  float r  = v0 * v0;
  #pragma unroll
  for (int k = 1; k < 12; ++k) {
    const float v  = p[8 * k];
    const float sq = v * v;
    r = r + sq;
  }
  r = r + __shfl_xor(r, 1);
  r = r + __shfl_xor(r, 2);
  r = r + __shfl_xor(r, 4);
  r = r + __shfl_xor(r, 8);
  r = r + __shfl_xor(r, 16);
  r = r + __shfl_xor(r, 32);
  if (lane == 0) x2[n] = r;
}

// ---------------------------------------------------------------------------
// K2: bf16 MFMA GEMM (128x128 tile, BK=32) + per-(row, 128-code block) top-2
//     of approx v = -2*dot_bf16 — unchanged from round 4 (proven).
// ---------------------------------------------------------------------------
__global__ __launch_bounds__(256)
void gemm1(const ushort_t* __restrict__ zh, const ushort_t* __restrict__ eh,
           float4* __restrict__ subtop) {
  __shared__ __align__(16) ushort_t Ash[128 * 32];
  __shared__ __align__(16) ushort_t Bsh[128 * 32];
  __shared__ float4 ltop[128][2];

  const int t    = threadIdx.x;
  const int w    = t >> 6, lane = t & 63;
  const int wr   = w >> 1, wc = w & 1;
  const int row0 = blockIdx.y * 128;
  const int col0 = blockIdx.x * 128;

  f32x4 acc[4][4];
  #pragma unroll
  for (int m = 0; m < 4; ++m)
    #pragma unroll
    for (int n = 0; n < 4; ++n) acc[m][n] = (f32x4){0.f, 0.f, 0.f, 0.f};

  const int rbase = w * 32 + (lane >> 2);
  const int jslot = lane & 3;

  for (int kk = 0; kk < DIM; kk += 32) {
    #pragma unroll
    for (int q = 0; q < 2; ++q) {
      const int r = rbase + q * 16;
      const int j = jslot ^ ((r >> 1) & 3);
      gload_lds16(zh + (size_t)(row0 + r) * DIM + kk + j * 8,
                  &Ash[w * 1024 + q * 512]);
      gload_lds16(eh + (size_t)(col0 + r) * DIM + kk + j * 8,
                  &Bsh[w * 1024 + q * 512]);
    }
    __syncthreads();
    short8v a[4], b[4];
    #pragma unroll
    for (int m = 0; m < 4; ++m) {
      const int r  = wr * 64 + m * 16 + (lane & 15);
      const int ja = (lane >> 4) ^ ((r >> 1) & 3);
      a[m] = *(const short8v*)&Ash[r * 32 + ja * 8];
      const int c  = wc * 64 + m * 16 + (lane & 15);
      const int jb = (lane >> 4) ^ ((c >> 1) & 3);
      b[m] = *(const short8v*)&Bsh[c * 32 + jb * 8];
    }
    #pragma unroll
    for (int m = 0; m < 4; ++m)
      #pragma unroll
      for (int n = 0; n < 4; ++n)
        acc[m][n] = __builtin_amdgcn_mfma_f32_16x16x32_bf16(a[m], b[n], acc[m][n], 0, 0, 0);
    __syncthreads();
  }

  #pragma unroll
  for (int m = 0; m < 4; ++m) {
    #pragma unroll
    for (int reg = 0; reg < 4; ++reg) {
      float v1 = FLT_MAX, v2 = FLT_MAX; int i1 = 0, i2 = 0;
      #pragma unroll
      for (int n = 0; n < 4; ++n) {
        const float v = -2.0f * acc[m][n][reg];
        const int   c = col0 + wc * 64 + n * 16 + (lane & 15);
        if (v < v1)      { v2 = v1; i2 = i1; v1 = v; i1 = c; }
        else if (v < v2) { v2 = v; i2 = c; }
      }
      #pragma unroll
      for (int off = 1; off < 16; off <<= 1) {
        const float ov1 = __shfl_xor(v1, off); const int oi1 = __shfl_xor(i1, off);
        const float ov2 = __shfl_xor(v2, off); const int oi2 = __shfl_xor(i2, off);
        if (ov1 < v1) {
          const float nv2 = (v1 < ov2) ? v1 : ov2;
          const int   ni2 = (v1 < ov2) ? i1 : oi2;
          v1 = ov1; i1 = oi1; v2 = nv2; i2 = ni2;
        } else if (ov1 < v2) { v2 = ov1; i2 = oi1; }
      }
      const int rloc = wr * 64 + m * 16 + (lane >> 4) * 4 + reg;
      if ((lane & 15) == 0)
        ltop[rloc][wc] = make_float4(v1, __int_as_float(i1), v2, __int_as_float(i2));
    }
  }
  __syncthreads();
  if (t < 128) {
    const float4 P = ltop[t][0], Q = ltop[t][1];
    float v1, v2; int i1, i2;
    if (P.x <= Q.x) {
      v1 = P.x; i1 = __float_as_int(P.y);
      v2 = (P.z < Q.x) ? P.z : Q.x;
      i2 = (P.z < Q.x) ? __float_as_int(P.w) : __float_as_int(Q.y);
    } else {
      v1 = Q.x; i1 = __float_as_int(Q.y);
      v2 = (Q.z < P.x) ? Q.z : P.x;
      i2 = (Q.z < P.x) ? __float_as_int(Q.w) : __float_as_int(P.y);
    }
    subtop[(size_t)(row0 + t) * 64 + blockIdx.x] =
        make_float4(v1, __int_as_float(i1), v2, __int_as_float(i2));
  }
}

// ---------------------------------------------------------------------------
// K3a: select — per row (1 wave): margin shortlist; if unique, winner is
//      proven (no rescore). Else lane-PARALLEL exact f32-chain rescore
//      (each lane handles its own <=2 candidates, dual ILP chains).
// ---------------------------------------------------------------------------
__global__ __launch_bounds__(256)
void select_k(const float* __restrict__ z, const float* __restrict__ emb,
              const float* __restrict__ x2, const float4* __restrict__ subtop,
              int* __restrict__ bcout) {
  const int lane = threadIdx.x & 63;
  const int n    = blockIdx.x * 4 + (threadIdx.x >> 6);

  const float4 e = subtop[(size_t)n * 64 + lane];
  const float v1 = e.x; const int i1 = __float_as_int(e.y);
  const float v2 = e.z; const int i2 = __float_as_int(e.w);

  float rowmin = v1;
  #pragma unroll
  for (int off = 32; off; off >>= 1) rowmin = fminf(rowmin, __shfl_xor(rowmin, off));
  const float thr = rowmin + MARGIN;

  const unsigned long long mA = __ballot(v1 <= thr);
  const unsigned long long mB = __ballot(v2 <= thr);
  const int ncand = __popcll(mA) + __popcll(mB);

  int winner;
  if (ncand == 1) {
    // unique shortlist member == exact argmin (margin covers approx error;
    // any exact-grid tie partner would also be inside the margin)
    winner = __shfl(i1, __builtin_ctzll(mA));
  } else {
    const float* zr  = z + (size_t)n * DIM;
    const float  x2n = x2[n];
    float bd = FLT_MAX; int bc = 0x7fffffff;
    if (v1 <= thr) {
      const int ca = i1;
      const int cb = (v2 <= thr) ? i2 : i1;   // dup chain when no 2nd cand
      const float* pa = emb + (size_t)ca * DIM;
      const float* pb = emb + (size_t)cb * DIM;
      float da = 0.f, db = 0.f;
      #pragma unroll 8
      for (int k = 0; k < DIM; ++k) {         // k-sequential fmaf chains (x2, ILP)
        const float zk = zr[k];
        da = fmaf(zk, pa[k], da);
        db = fmaf(zk, pb[k], db);
      }
      const float sa = x2n - 2.0f * da;
      const float sb = x2n - 2.0f * db;
      bd = sa; bc = ca;
      if (sb < bd || (sb == bd && cb < bc)) { bd = sb; bc = cb; }
    }
    #pragma unroll
    for (int off = 32; off; off >>= 1) {
      const float ov = __shfl_xor(bd, off);
      const int   oc = __shfl_xor(bc, off);
      if (ov < bd || (ov == bd && oc < bc)) { bd = ov; bc = oc; }
    }
    winner = bc;
  }
  if (lane == 0) bcout[n] = winner;
}

// ---------------------------------------------------------------------------
// K3b: emit — dense streaming: gather + straight-through + idx + loss
//      partial per BLOCK (no atomics), float4-vectorized.
// ---------------------------------------------------------------------------
__global__ __launch_bounds__(256)
void emit_k(const float* __restrict__ z, const float* __restrict__ emb,
            const int* __restrict__ bcin, float* __restrict__ out,
            double* __restrict__ partials) {
  __shared__ double wsum[4];
  const int w    = threadIdx.x >> 6;
  const int lane = threadIdx.x & 63;
  const int n    = blockIdx.x * 4 + w;

  const int bc = bcin[n];
  const float4* zr = (const float4*)(z + (size_t)n * DIM);
  const float4* er = (const float4*)(emb + (size_t)bc * DIM);
  float4* outr = (float4*)(out + (size_t)n * DIM);

  double lsum = 0.0;
  #pragma unroll
  for (int i = 0; i < 3; ++i) {
    const int idx = lane + 64 * i;          // 192 float4 per row
    const float4 zz = zr[idx];
    const float4 qq = er[idx];
    float4 o;
    o.x = zz.x + (qq.x - zz.x); o.y = zz.y + (qq.y - zz.y);
    o.z = zz.z + (qq.z - zz.z); o.w = zz.w + (qq.w - zz.w);
    outr[idx] = o;
    const float dx = qq.x - zz.x, dy = qq.y - zz.y;
    const float dz = qq.z - zz.z, dw = qq.w - zz.w;
    lsum = fma((double)dx, (double)dx, lsum);
    lsum = fma((double)dy, (double)dy, lsum);
    lsum = fma((double)dz, (double)dz, lsum);
    lsum = fma((double)dw, (double)dw, lsum);
  }
  #pragma unroll
  for (int off = 32; off; off >>= 1) lsum += __shfl_xor(lsum, off);
  if (lane == 0) {
    out[(size_t)NROWS * DIM + n] = (float)bc;   // indices as f32 values
    wsum[w] = lsum;
  }
  __syncthreads();
  if (threadIdx.x == 0)
    partials[blockIdx.x] = ((wsum[0] + wsum[1]) + (wsum[2] + wsum[3]));
}

// ---------------------------------------------------------------------------
// K4: deterministic 2-level loss reduce: 4096 partials -> loss
// ---------------------------------------------------------------------------
__global__ __launch_bounds__(256)
void fin_kernel(const double* __restrict__ partials, float* __restrict__ out) {
  __shared__ double red[256];
  const int t = threadIdx.x;
  double s = 0.0;
  #pragma unroll
  for (int i = 0; i < NBLK_EMIT / 256; ++i) s += partials[t * (NBLK_EMIT / 256) + i];
  red[t] = s;
  __syncthreads();
  for (int off = 128; off; off >>= 1) {
    if (t < off) red[t] += red[t + off];
    __syncthreads();
  }
  if (t == 0)
    out[(size_t)NROWS * DIM + NROWS] =
        (float)(0.25 * red[0] / (double)((size_t)NROWS * DIM));
}

extern "C" void kernel_launch(void* const* d_in, const int* in_sizes, int n_in,
                              void* d_out, int out_size, void* d_ws, size_t ws_size,
                              hipStream_t stream) {
  const float* z   = (const float*)d_in[0];
  const float* emb = (const float*)d_in[1];
  float* out = (float*)d_out;
  char*  ws  = (char*)d_ws;

  // ws: partials 32KB | x2 64KB | bc 64KB | zh 24MB | eh 12MB | subtop 16MB
  double*   partials = (double*)ws;
  float*    x2       = (float*)(ws + 32768);
  int*      bc       = (int*)(ws + 98304);
  ushort_t* zh       = (ushort_t*)(ws + 163840);
  ushort_t* eh       = (ushort_t*)(ws + 25329664);
  float4*   subtop   = (float4*)(ws + 37912576);

  cvt_kernel<<<(NROWS * DIM / 8 + 255) / 256, 256, 0, stream>>>(z, zh, NROWS * DIM / 8);
  cvt_kernel<<<(KC * DIM / 8 + 255) / 256, 256, 0, stream>>>(emb, eh, KC * DIM / 8);
  x2_kernel<<<NROWS / 4, 256, 0, stream>>>(z, x2);
  gemm1<<<dim3(KC / 128, NROWS / 128), 256, 0, stream>>>(zh, eh, subtop);
  select_k<<<NROWS / 4, 256, 0, stream>>>(z, emb, x2, subtop, bc);
  emit_k<<<NBLK_EMIT, 256, 0, stream>>>(z, emb, bc, out, partials);
  fin_kernel<<<1, 256, 0, stream>>>(partials, out);
}